// Round 17
// baseline (375.583 us; speedup 1.0000x reference)
//
#include <hip/hip_runtime.h>

// CausalSelfAttention: B=2, S=2048, H=2048, NH=16, HD=128. f32 in/out, bf16 MFMA inside.
// R24 = R23 (best, 371.7us) + out-proj ported to the twice-verified 8-phase
// counted-vmcnt schedule (gemm8o). Measurement lesson from R23: rocprof replay
// inflates deep-pipelined kernels (gemm8q showed 147us profiled but the TOTAL
// dropped 391->371.7, i.e. real QKV ~100us); judge by bench total.
// gemm8o: 256x128 tile, NJ=2, grid 256 = 1 exact round, LDS 96KB.
// Ledger mirrors gemm8q with B-thirds->B-halves (6 ops/tile): prologue 9 + vm3;
// stages ph1:A1hi+B1hi(t+1) | ph3:A0lo(t+2) | ph4:B0lo(t+2)+vm3 |
// ph5:A0hi+B0hi(t+2) | ph7:A1lo(t+3) | ph8:B1lo(t+3)+vm3. vm3 completes exactly
// the next tile's 6 ops; never drains. Contiguous-half read/stage discipline
// (the R22-race fix): A-halves read ph1-2/ph3-4, staged ph3/ph5; B fully read
// by ph2, staged ph4/ph5. QKV gemm8q / attn R17 / convert_all: frozen from R23.

using bf16x8 = __attribute__((ext_vector_type(8))) short;
using bf16x4 = __attribute__((ext_vector_type(4))) short;
using f32x4  = __attribute__((ext_vector_type(4))) float;

#define S_LEN 2048
#define NHEAD 16
#define HDIM  128
#define HID   2048

__device__ __forceinline__ unsigned short f2bf(float f) {
    unsigned int u = __float_as_uint(f);
    u += 0x7fffu + ((u >> 16) & 1u);   // round-to-nearest-even
    return (unsigned short)(u >> 16);
}
__device__ __forceinline__ void gl2lds16(const void* g, void* l) {
    __builtin_amdgcn_global_load_lds(
        (const __attribute__((address_space(1))) void*)g,
        (__attribute__((address_space(3))) void*)l, 16, 0, 0);
}

// 16x16x16 bf16 MFMA, device-guarded (host pass must not reference the builtin).
__device__ __forceinline__ f32x4 pv_mfma(bf16x4 a, bf16x4 b, f32x4 c) {
#if defined(__HIP_DEVICE_COMPILE__)
#if __has_builtin(__builtin_amdgcn_mfma_f32_16x16x16bf16_1k)
    return __builtin_amdgcn_mfma_f32_16x16x16bf16_1k(a, b, c, 0, 0, 0);
#else
    asm("v_mfma_f32_16x16x16_bf16 %0, %1, %2, %0" : "+v"(c) : "v"(a), "v"(b));
    return c;
#endif
#else
    (void)a; (void)b;
    return c;
#endif
}

// --------------------------------- fused converts: x f32->bf16, weights f32->bf16^T
__global__ void convert_all(const float* __restrict__ x,
                            const float* __restrict__ w0, const float* __restrict__ w1,
                            const float* __restrict__ w2, const float* __restrict__ w3,
                            unsigned short* __restrict__ xb,
                            unsigned short* __restrict__ t0, unsigned short* __restrict__ t1,
                            unsigned short* __restrict__ t2, unsigned short* __restrict__ t3) {
    int z = blockIdx.z;
    if (z >= 4) {
        int lin = (z - 4) * 1024 + blockIdx.y * 32 + blockIdx.x;   // 0..8191
        int i = (lin * 256 + threadIdx.x) * 4;
        float4 v = *(const float4*)(x + i);
        ushort4 o;
        o.x = f2bf(v.x); o.y = f2bf(v.y); o.z = f2bf(v.z); o.w = f2bf(v.w);
        *(ushort4*)(xb + i) = o;
        return;
    }
    __shared__ float tile[64][65];
    const float* src = (z == 0) ? w0 : (z == 1) ? w1 : (z == 2) ? w2 : w3;
    unsigned short* dst = (z == 0) ? t0 : (z == 1) ? t1 : (z == 2) ? t2 : t3;
    int r0 = blockIdx.y * 64, c0 = blockIdx.x * 64;
    int t = threadIdx.x;
    for (int i = t; i < 64 * 64; i += 256) {
        int r = i >> 6, c = i & 63;
        tile[r][c] = src[(size_t)(r0 + r) * HID + c0 + c];
    }
    __syncthreads();
    for (int i = t; i < 64 * 64; i += 256) {
        int r = i & 63, c = i >> 6;
        dst[(size_t)(c0 + c) * HID + r0 + r] = f2bf(tile[r][c]);
    }
}

// ---- counted waits -----------------------------------------------------------
__device__ __forceinline__ void sched0() { __builtin_amdgcn_sched_barrier(0); }
__device__ __forceinline__ void w_lgkm0() { asm volatile("s_waitcnt lgkmcnt(0)" ::: "memory"); sched0(); }
__device__ __forceinline__ void w_vm4() { asm volatile("s_waitcnt vmcnt(4)" ::: "memory"); sched0(); }
__device__ __forceinline__ void w_vm3() { asm volatile("s_waitcnt vmcnt(3)" ::: "memory"); sched0(); }
__device__ __forceinline__ void w_vm2() { asm volatile("s_waitcnt vmcnt(2)" ::: "memory"); sched0(); }
__device__ __forceinline__ void w_vm0() { asm volatile("s_waitcnt vmcnt(0)" ::: "memory"); sched0(); }
__device__ __forceinline__ void barx() {
    asm volatile("" ::: "memory");
    __builtin_amdgcn_s_barrier();
    asm volatile("" ::: "memory");
}

// ---------------------------------------------------------------- QKV GEMM 8-phase (R23, frozen)
// C[4096][6144] = A @ Bt^T + bias (fused QKV, Bt = contiguous [6144][2048]).
// 256x192 tile, BK=64, 8 waves 2x4, LDS 112KB, grid 512 = 2 exact rounds.
// A fragment rows = hm*128 + wr*64 + mi*16 + l15 (hm = CONTIGUOUS staging half).
__launch_bounds__(512, 2)
__global__ void gemm8q(const unsigned short* __restrict__ A,
                       const unsigned short* __restrict__ Bt,
                       const float* __restrict__ bias0,
                       const float* __restrict__ bias1,
                       const float* __restrict__ bias2,
                       unsigned short* __restrict__ C0,
                       unsigned short* __restrict__ C1,
                       unsigned short* __restrict__ C2) {
    __shared__ __align__(16) unsigned short lds[57344];   // 112KB
    unsigned short* const A0 = lds;            // A: 256x64 = 16384 elems per buf
    unsigned short* const A1 = lds + 16384;
    unsigned short* const B0 = lds + 32768;    // B: 192x64 = 12288 elems per buf
    unsigned short* const B1 = lds + 45056;

    int vb = (blockIdx.x & 7) * 64 + (blockIdx.x >> 3);   // 512 blocks, bijective
    int m0  = (vb & 15) * 256;
    int n0g = (vb >> 4) * 192;

    int tid = threadIdx.x;
    int lane = tid & 63;
    int wv_ = tid >> 6;
    int wr = wv_ >> 2, wc = wv_ & 3;            // 2x4 wave grid
    int l15 = lane & 15, quad = lane >> 4;

    int tr = tid >> 3;
    int tc = ((tid & 7) ^ (tr & 7)) << 3;
    const unsigned short* gA = A  + (size_t)(m0  + tr) * HID + tc;
    const unsigned short* gB = Bt + (size_t)(n0g + tr) * HID + tc;
    const int td8 = tid * 8;

    int arow0 = (wr * 64 + l15) * 64;           // + hm*8192 + mi*1024
    int brow0 = (wc * 48 + l15) * 64;           // + nj*1024
    int swz[2] = { ((quad ^ (l15 & 7)) << 3), (((4 + quad) ^ (l15 & 7)) << 3) };

    f32x4 acc[8][3];
#pragma unroll
    for (int i = 0; i < 8; ++i)
#pragma unroll
        for (int j = 0; j < 3; ++j) acc[i][j] = (f32x4){0.f, 0.f, 0.f, 0.f};

    bf16x8 av[4];
    bf16x8 bv[2][3];

#define SGA(kt, half, AD) do {                                               \
    size_t _g = (size_t)((half) * 128) * HID + (size_t)(kt) * 64;            \
    gl2lds16(gA + _g,            (AD) + (half) * 8192 + td8);                \
    gl2lds16(gA + _g + 64 * HID, (AD) + (half) * 8192 + 4096 + td8); } while (0)

#define SGB3(kt, third, BD) do {                                             \
    size_t _g = (size_t)((third) * 64) * HID + (size_t)(kt) * 64;            \
    gl2lds16(gB + _g, (BD) + (third) * 4096 + td8); } while (0)

#define RDA(AD, hm, kk) do {                                                 \
    _Pragma("unroll")                                                        \
    for (int mi = 0; mi < 4; ++mi)                                           \
        av[mi] = *(const bf16x8*)((AD) + arow0 + (hm) * 8192                 \
                                  + mi * 1024 + swz[kk]); } while (0)

#define RDB(BD, kk) do {                                                     \
    _Pragma("unroll")                                                        \
    for (int nj = 0; nj < 3; ++nj)                                           \
        bv[kk][nj] = *(const bf16x8*)((BD) + brow0 + nj * 1024 + swz[kk]); } while (0)

#define MFQ(hm, kk) do {                                                     \
    __builtin_amdgcn_s_setprio(1);                                           \
    _Pragma("unroll")                                                        \
    for (int mi = 0; mi < 4; ++mi)                                           \
        _Pragma("unroll")                                                    \
        for (int nj = 0; nj < 3; ++nj)                                       \
            acc[(hm) * 4 + mi][nj] =                                         \
                __builtin_amdgcn_mfma_f32_16x16x32_bf16(av[mi], bv[kk][nj],  \
                    acc[(hm) * 4 + mi][nj], 0, 0, 0);                        \
    __builtin_amdgcn_s_setprio(0); sched0(); } while (0)

    SGA(0, 0, A0); SGA(0, 1, A0);
    SGB3(0, 0, B0); SGB3(0, 1, B0); SGB3(0, 2, B0);
    SGA(1, 0, A1); SGB3(1, 0, B1); SGB3(1, 1, B1);
    w_vm4();
    barx();

    for (int it = 0; it < 16; ++it) {
        int t  = 2 * it;
        int t2 = (t + 2 < 32) ? t + 2 : 31;
        int t3 = (t + 3 < 32) ? t + 3 : 31;
        RDA(A0, 0, 0); RDB(B0, 0);
        SGA(t + 1, 1, A1); SGB3(t + 1, 2, B1);
        barx(); w_lgkm0();
        MFQ(0, 0);
        barx();
        RDA(A0, 0, 1); RDB(B0, 1);
        barx(); w_lgkm0();
        MFQ(0, 1);
        barx();
        RDA(A0, 1, 0);
        SGA(t2, 0, A0);
        barx(); w_lgkm0();
        MFQ(1, 0);
        barx();
        RDA(A0, 1, 1);
        SGB3(t2, 0, B0); SGB3(t2, 1, B0);
        barx(); w_lgkm0();
        MFQ(1, 1);
        w_vm4();
        barx();
        RDA(A1, 0, 0); RDB(B1, 0);
        SGA(t2, 1, A0); SGB3(t2, 2, B0);
        barx(); w_lgkm0();
        MFQ(0, 0);
        barx();
        RDA(A1, 0, 1); RDB(B1, 1);
        barx(); w_lgkm0();
        MFQ(0, 1);
        barx();
        RDA(A1, 1, 0);
        SGA(t3, 0, A1);
        barx(); w_lgkm0();
        MFQ(1, 0);
        barx();
        RDA(A1, 1, 1);
        SGB3(t3, 0, B1); SGB3(t3, 1, B1);
        barx(); w_lgkm0();
        MFQ(1, 1);
        w_vm4();
        barx();
    }
    asm volatile("s_waitcnt vmcnt(0) lgkmcnt(0)" ::: "memory");

#undef SGA
#undef SGB3
#undef RDA
#undef RDB
#undef MFQ

#pragma unroll
    for (int j = 0; j < 3; ++j) {
        int n = n0g + wc * 48 + j * 16 + l15;
        int zj = n >> 11;
        int nn = n & 2047;
        float bn = (zj == 0) ? bias0[nn] : (zj == 1) ? bias1[nn] : bias2[nn];
        unsigned short* Cz = (zj == 0) ? C0 : (zj == 1) ? C1 : C2;
#pragma unroll
        for (int i = 0; i < 8; ++i) {
            int mb = m0 + (i >> 2) * 128 + wr * 64 + (i & 3) * 16 + quad * 4;
            if (zj == 2) {
                int b = mb >> 11, s = mb & 2047, h = nn >> 7, d = nn & 127;
                int kt = s >> 4, qv = (s >> 2) & 3, ct = d >> 4, lv = d & 15;
                size_t addr = ((((size_t)((b << 4) + h) * 128 + kt) * 4 + (ct >> 1)) * 4 + qv) * 128
                              + lv * 8 + (ct & 1) * 4;
                ushort4 o;
                o.x = f2bf(acc[i][j][0] + bn);
                o.y = f2bf(acc[i][j][1] + bn);
                o.z = f2bf(acc[i][j][2] + bn);
                o.w = f2bf(acc[i][j][3] + bn);
                *(ushort4*)&Cz[addr] = o;
            } else {
#pragma unroll
                for (int reg = 0; reg < 4; ++reg) {
                    int m = mb + reg;
                    float v = acc[i][j][reg] + bn;
                    int b = m >> 11, s = m & 2047, h = nn >> 7, d = nn & 127;
                    if (zj == 1) {
                        int kt = s >> 4, lk = s & 15, kk = d >> 5, qk = (d >> 3) & 3, e = d & 7;
                        size_t addr = ((((size_t)((b << 4) + h) * 128 + kt) * 4 + kk) * 4 + qk) * 128
                                      + lk * 8 + e;
                        Cz[addr] = f2bf(v);
                    } else {
                        Cz[(size_t)(((b << 4) + h) * S_LEN + s) * HDIM + d] = f2bf(v);
                    }
                }
            }
        }
    }
}

// ---------------------------------------------------------------- out-proj GEMM 8-phase (R24)
// Cf[4096][2048] = A @ Bt^T + bias, f32 out. 256x128 tile, NJ=2, grid 256 = 1 round.
// Strict mirror of gemm8q with B-halves (1 op each); 6 ops/tile; vm3 at ph4/ph8.
__launch_bounds__(512, 2)
__global__ void gemm8o(const unsigned short* __restrict__ A,
                       const unsigned short* __restrict__ Bt,
                       const float* __restrict__ bias0,
                       float* __restrict__ Cf) {
    __shared__ __align__(16) unsigned short lds[49152];   // 96KB
    unsigned short* const A0 = lds;            // A: 256x64 = 16384 elems per buf
    unsigned short* const A1 = lds + 16384;
    unsigned short* const B0 = lds + 32768;    // B: 128x64 = 8192 elems per buf
    unsigned short* const B1 = lds + 40960;

    int vb = (blockIdx.x & 7) * 32 + (blockIdx.x >> 3);   // 256 blocks, bijective
    int m0  = (vb & 15) * 256;
    int n0g = (vb >> 4) * 128;

    int tid = threadIdx.x;
    int lane = tid & 63;
    int wv_ = tid >> 6;
    int wr = wv_ >> 2, wc = wv_ & 3;            // 2x4 wave grid
    int l15 = lane & 15, quad = lane >> 4;

    int tr = tid >> 3;
    int tc = ((tid & 7) ^ (tr & 7)) << 3;
    const unsigned short* gA = A  + (size_t)(m0  + tr) * HID + tc;
    const unsigned short* gB = Bt + (size_t)(n0g + tr) * HID + tc;
    const int td8 = tid * 8;

    int arow0 = (wr * 64 + l15) * 64;           // + hm*8192 + mi*1024
    int brow0 = (wc * 32 + l15) * 64;           // + nj*1024
    int swz[2] = { ((quad ^ (l15 & 7)) << 3), (((4 + quad) ^ (l15 & 7)) << 3) };

    f32x4 acc[8][2];
#pragma unroll
    for (int i = 0; i < 8; ++i)
#pragma unroll
        for (int j = 0; j < 2; ++j) acc[i][j] = (f32x4){0.f, 0.f, 0.f, 0.f};

    bf16x8 av[4];
    bf16x8 bv[2][2];

#define SGA(kt, half, AD) do {                                               \
    size_t _g = (size_t)((half) * 128) * HID + (size_t)(kt) * 64;            \
    gl2lds16(gA + _g,            (AD) + (half) * 8192 + td8);                \
    gl2lds16(gA + _g + 64 * HID, (AD) + (half) * 8192 + 4096 + td8); } while (0)

#define SGB2(kt, half, BD) do {                                              \
    size_t _g = (size_t)((half) * 64) * HID + (size_t)(kt) * 64;             \
    gl2lds16(gB + _g, (BD) + (half) * 4096 + td8); } while (0)

#define RDA(AD, hm, kk) do {                                                 \
    _Pragma("unroll")                                                        \
    for (int mi = 0; mi < 4; ++mi)                                           \
        av[mi] = *(const bf16x8*)((AD) + arow0 + (hm) * 8192                 \
                                  + mi * 1024 + swz[kk]); } while (0)

#define RDB(BD, kk) do {                                                     \
    _Pragma("unroll")                                                        \
    for (int nj = 0; nj < 2; ++nj)                                           \
        bv[kk][nj] = *(const bf16x8*)((BD) + brow0 + nj * 1024 + swz[kk]); } while (0)

#define MFQ(hm, kk) do {                                                     \
    __builtin_amdgcn_s_setprio(1);                                           \
    _Pragma("unroll")                                                        \
    for (int mi = 0; mi < 4; ++mi)                                           \
        _Pragma("unroll")                                                    \
        for (int nj = 0; nj < 2; ++nj)                                       \
            acc[(hm) * 4 + mi][nj] =                                         \
                __builtin_amdgcn_mfma_f32_16x16x32_bf16(av[mi], bv[kk][nj],  \
                    acc[(hm) * 4 + mi][nj], 0, 0, 0);                        \
    __builtin_amdgcn_s_setprio(0); sched0(); } while (0)

    // prologue: tile0 full (6 ops) + tile1 {A-lo(2), B-lo(1)} = 9; vm3 -> oldest 6 = tile0.
    SGA(0, 0, A0); SGA(0, 1, A0);
    SGB2(0, 0, B0); SGB2(0, 1, B0);
    SGA(1, 0, A1); SGB2(1, 0, B1);
    w_vm3();
    barx();

    for (int it = 0; it < 16; ++it) {
        int t  = 2 * it;
        int t2 = (t + 2 < 32) ? t + 2 : 31;
        int t3 = (t + 3 < 32) ? t + 3 : 31;
        // ph1 (A-lo,k0) tile t; stage A1hi + B1hi (t+1): vm 3->6
        RDA(A0, 0, 0); RDB(B0, 0);
        SGA(t + 1, 1, A1); SGB2(t + 1, 1, B1);
        barx(); w_lgkm0();
        MFQ(0, 0);
        barx();
        // ph2 (A-lo,k1)  [A-lo + all B fully read]
        RDA(A0, 0, 1); RDB(B0, 1);
        barx(); w_lgkm0();
        MFQ(0, 1);
        barx();
        // ph3 (A-hi,k0); stage A0lo(t+2): vm 6->8
        RDA(A0, 1, 0);
        SGA(t2, 0, A0);
        barx(); w_lgkm0();
        MFQ(1, 0);
        barx();
        // ph4 (A-hi,k1); stage B0lo(t+2): vm 8->9; vm3 certifies tile t+1 (6 ops)
        RDA(A0, 1, 1);
        SGB2(t2, 0, B0);
        barx(); w_lgkm0();
        MFQ(1, 1);
        w_vm3();
        barx();
        // ph5 (A-lo,k0) tile t+1; stage A0hi + B0hi (t+2): vm 3->6
        RDA(A1, 0, 0); RDB(B1, 0);
        SGA(t2, 1, A0); SGB2(t2, 1, B0);
        barx(); w_lgkm0();
        MFQ(0, 0);
        barx();
        // ph6 (A-lo,k1)
        RDA(A1, 0, 1); RDB(B1, 1);
        barx(); w_lgkm0();
        MFQ(0, 1);
        barx();
        // ph7 (A-hi,k0); stage A1lo(t+3): vm 6->8
        RDA(A1, 1, 0);
        SGA(t3, 0, A1);
        barx(); w_lgkm0();
        MFQ(1, 0);
        barx();
        // ph8 (A-hi,k1); stage B1lo(t+3): vm 8->9; vm3 certifies tile t+2 (buf0)
        RDA(A1, 1, 1);
        SGB2(t3, 0, B1);
        barx(); w_lgkm0();
        MFQ(1, 1);
        w_vm3();
        barx();
    }
    asm volatile("s_waitcnt vmcnt(0) lgkmcnt(0)" ::: "memory");

#undef SGA
#undef SGB2
#undef RDA
#undef RDB
#undef MFQ

    // epilogue: f32 row-major; row map i=(hm*4+mi) -> hm*128 + wr*64 + mi*16
#pragma unroll
    for (int j = 0; j < 2; ++j) {
        int n = n0g + wc * 32 + j * 16 + l15;
        float bn = bias0[n];
#pragma unroll
        for (int i = 0; i < 8; ++i) {
            int mb = m0 + (i >> 2) * 128 + wr * 64 + (i & 3) * 16 + quad * 4;
#pragma unroll
            for (int reg = 0; reg < 4; ++reg) {
                int m = mb + reg;
                Cf[(size_t)m * HID + n] = acc[i][j][reg] + bn;
            }
        }
    }
}

// ---------------------------------------------------------------- flash attention (R17, frozen)
__launch_bounds__(256, 2)
__global__ void attn_kernel(const unsigned short* __restrict__ Qg,
                            const unsigned short* __restrict__ Kp,
                            const unsigned short* __restrict__ Vp,
                            unsigned short* __restrict__ O) {
    __shared__ __align__(16) unsigned short kv[2][4096];   // [buf][K:0..2048 | V:2048..4096]

    int linear = blockIdx.x;                  // 0..511
    int xcd = linear & 7;
    int u = linear >> 3;                      // 0..63
    int bh = xcd * 4 + (u & 3);               // 4 bh per XCD (K/V 4MB ~ L2)
    int q = u >> 2;                           // 0..15 -> pair (q, 31-q)
    int b = bh >> 4, h = bh & 15;

    int tid = threadIdx.x, lane = tid & 63, w = tid >> 6;
    int l15 = lane & 15, quad = lane >> 4;

    const unsigned short* Qb = Qg + (size_t)bh * (S_LEN * HDIM);
    const unsigned short* Kg = Kp + (size_t)bh * 262144;
    const unsigned short* Vg = Vp + (size_t)bh * 262144;
    const float k2 = 0.08838834764831845f * 1.4426950408889634f;  // scale*log2(e)

    const int frag = quad * 128 + l15 * 8;    // in-tile fragment offset (elems)
    const int td8 = tid * 8;                  // staging offset: tid*16B

#define VLO(x) __builtin_shufflevector(x, x, 0, 1, 2, 3)
#define VHI(x) __builtin_shufflevector(x, x, 4, 5, 6, 7)
#define ASTAGE(kt, bf) do { size_t _g = (size_t)(kt) * 2048 + td8;             \
    gl2lds16(Kg + _g, &kv[bf][td8]);                                           \
    gl2lds16(Vg + _g, &kv[bf][2048 + td8]); } while (0)

    auto run_qblock = [&](int qb) {
        int s  = 4 * qb + w;                  // my strip (diagonal tile = s)
        int r0 = s * 16;
        int N  = 4 * qb + 4;                  // staged tiles (block-uniform)

        bf16x8 qf[4];
#pragma unroll
        for (int kk = 0; kk < 4; ++kk)
            qf[kk] = *(const bf16x8*)&Qb[(size_t)(r0 + l15) * HDIM + kk * 32 + quad * 8];

        f32x4 o_acc[8];
#pragma unroll
        for (int c = 0; c < 8; ++c) o_acc[c] = (f32x4){0.f, 0.f, 0.f, 0.f};
        float l_part = 0.f;

        ASTAGE(0, 0);
        for (int kt = 0; kt < N; ++kt) {
            int nk = (kt + 1 < N) ? kt + 1 : kt;      // uniform dummy re-stage at end
            ASTAGE(nk, (kt + 1) & 1);
            w_vm2();                                  // my 2 ops of stage(kt) done
            barx();                                   // all waves: tile kt staged

            const unsigned short* KL = &kv[kt & 1][frag];
            const unsigned short* VL = &kv[kt & 1][2048 + frag];
            bf16x8 kb0 = *(const bf16x8*)(KL);
            bf16x8 kb1 = *(const bf16x8*)(KL + 512);
            bf16x8 kb2 = *(const bf16x8*)(KL + 1024);
            bf16x8 kb3 = *(const bf16x8*)(KL + 1536);
            bf16x8 v0 = *(const bf16x8*)(VL);
            bf16x8 v1 = *(const bf16x8*)(VL + 512);
            bf16x8 v2 = *(const bf16x8*)(VL + 1024);
            bf16x8 v3 = *(const bf16x8*)(VL + 1536);

            f32x4 st0 = (f32x4){0.f, 0.f, 0.f, 0.f};
            f32x4 st1 = (f32x4){0.f, 0.f, 0.f, 0.f};
            __builtin_amdgcn_s_setprio(1);
            st0 = __builtin_amdgcn_mfma_f32_16x16x32_bf16(kb0, qf[0], st0, 0, 0, 0);
            st1 = __builtin_amdgcn_mfma_f32_16x16x32_bf16(kb1, qf[1], st1, 0, 0, 0);
            st0 = __builtin_amdgcn_mfma_f32_16x16x32_bf16(kb2, qf[2], st0, 0, 0, 0);
            st1 = __builtin_amdgcn_mfma_f32_16x16x32_bf16(kb3, qf[3], st1, 0, 0, 0);
            __builtin_amdgcn_s_setprio(0);
            f32x4 stv = st0 + st1;

            float p0, p1, p2, p3;
            int doff = kt - s;                        // wave-uniform
            if (doff >= 0) {
                int d16 = doff << 4;
                p0 = (d16 + quad * 4 + 0 <= l15) ? exp2f(stv[0] * k2) : 0.f;
                p1 = (d16 + quad * 4 + 1 <= l15) ? exp2f(stv[1] * k2) : 0.f;
                p2 = (d16 + quad * 4 + 2 <= l15) ? exp2f(stv[2] * k2) : 0.f;
                p3 = (d16 + quad * 4 + 3 <= l15) ? exp2f(stv[3] * k2) : 0.f;
            } else {
                p0 = exp2f(stv[0] * k2); p1 = exp2f(stv[1] * k2);
                p2 = exp2f(stv[2] * k2); p3 = exp2f(stv[3] * k2);
            }
            l_part += (p0 + p1) + (p2 + p3);

            bf16x4 pf;
            pf[0] = (short)f2bf(p0); pf[1] = (short)f2bf(p1);
            pf[2] = (short)f2bf(p2); pf[3] = (short)f2bf(p3);

            __builtin_amdgcn_s_setprio(1);
            o_acc[0] = pv_mfma(pf, VLO(v0), o_acc[0]);
            o_acc[1] = pv_mfma(pf, VHI(v0), o_acc[1]);
            o_acc[2] = pv_mfma(pf, VLO(v1), o_acc[2]);
            o_acc[3] = pv_mfma(pf, VHI(v1), o_acc[3]);
            o_acc[4] = pv_mfma(pf, VLO(v2), o_acc[4]);
            o_acc[5] = pv_mfma(pf, VHI(v2), o_acc[5]);
            o_acc[6] = pv_mfma(pf, VLO(v3), o_acc[6]);
            o_acc[7] = pv_mfma(pf, VHI(v3), o_acc[7]);
            __builtin_amdgcn_s_setprio(0);
            barx();                                   // reads of buf[kt&1] done
        }
        w_vm0();                                      // drain dummy stage
        barx();                                       // buffers clean for next qblock

        float lp = l_part;
        lp += __shfl_xor(lp, 16, 64);
        lp += __shfl_xor(lp, 32, 64);
#pragma unroll
        for (int reg = 0; reg < 4; ++reg) {
            float l = __shfl(lp, quad * 4 + reg, 64);
            float inv = 1.f / l;
            int srow = r0 + quad * 4 + reg;
            unsigned short* op = O + (size_t)(b * S_LEN + srow) * HID + h * HDIM;
#pragma unroll
            for (int ct = 0; ct < 8; ++ct)
                op[ct * 16 + l15] = f2bf(o_acc[ct][reg] * inv);
        }
    };

    run_qblock(q);        // 4q+4 tiles
    run_qblock(31 - q);   // 128-4q tiles  (total 132, every block)

#undef ASTAGE
#undef VLO
#undef VHI
}

// ---------------------------------------------------------------- launch
extern "C" void kernel_launch(void* const* d_in, const int* in_sizes, int n_in,
                              void* d_out, int out_size, void* d_ws, size_t ws_size,
                              hipStream_t stream) {
    (void)in_sizes; (void)n_in; (void)out_size; (void)ws_size;
    const float* x  = (const float*)d_in[0];
    const float* wq = (const float*)d_in[2];
    const float* bq = (const float*)d_in[3];
    const float* wk = (const float*)d_in[4];
    const float* bk = (const float*)d_in[5];
    const float* wv = (const float*)d_in[6];
    const float* bv = (const float*)d_in[7];
    const float* wo = (const float*)d_in[8];
    const float* bo = (const float*)d_in[9];
    float* out = (float*)d_out;

    unsigned short* ws = (unsigned short*)d_ws;
    const size_t WSZ = 4194304;
    unsigned short* wqT = ws;                // [0, 4M)   wqT/wkT/wvT contiguous =
    unsigned short* wkT = ws + WSZ;          // [4M, 8M)  fused [6144][2048] B for QKV
    unsigned short* wvT = ws + 2 * WSZ;      // [8M, 12M)
    unsigned short* woT = ws + 3 * WSZ;      // [12M, 16M)
    unsigned short* xb  = ws + 4 * WSZ;      // [16M, 24M)
    unsigned short* Ab  = ws + 4 * WSZ;      // aliases xb (dead after QKV gemm)
    unsigned short* Qb  = ws + 6 * WSZ;      // [24M, 32M)
    unsigned short* Kb  = ws + 8 * WSZ;      // [32M, 40M)  fragment-packed
    unsigned short* Vb  = ws + 10 * WSZ;     // [40M, 48M)  fragment-packed

    convert_all<<<dim3(32, 32, 12), 256, 0, stream>>>(x, wq, wk, wv, wo,
                                                      xb, wqT, wkT, wvT, woT);
    gemm8q<<<dim3(512), 512, 0, stream>>>(xb, wqT, bq, bk, bv, Qb, Kb, Vb);
    attn_kernel<<<dim3(512), 256, 0, stream>>>(Qb, Kb, Vb, Ab);
    gemm8o<<<dim3(256), 512, 0, stream>>>(Ab, woT, bo, out);
}